// Round 1
// baseline (5772.688 us; speedup 1.0000x reference)
//
#include <hip/hip_runtime.h>
#include <hip/hip_bf16.h>

#define N_NODES 100000
#define N_EDGES 1600000
// IN_CH=256, HID_CH=128, OUT_CH=64

// ---------------- gcn_norm kernels ----------------

__global__ void zero_f32(float* __restrict__ p, int n) {
    int i = blockIdx.x * 256 + threadIdx.x;
    if (i < n) p[i] = 0.0f;
}

__global__ void scatter_deg(const int* __restrict__ dst, const float* __restrict__ ew,
                            float* __restrict__ deg) {
    int e = blockIdx.x * 256 + threadIdx.x;
    if (e < N_EDGES) unsafeAtomicAdd(&deg[dst[e]], ew[e]);
}

// deg -> dis in place. Self-loop adds weight 1 to every node, so deg+1 >= 1.
__global__ void compute_dis(float* __restrict__ deg) {
    int n = blockIdx.x * 256 + threadIdx.x;
    if (n < N_NODES) deg[n] = rsqrtf(deg[n] + 1.0f);
}

__global__ void compute_norm(const int* __restrict__ src, const int* __restrict__ dst,
                             const float* __restrict__ ew, const float* __restrict__ dis,
                             float* __restrict__ norm) {
    int e = blockIdx.x * 256 + threadIdx.x;
    if (e < N_EDGES) norm[e] = dis[src[e]] * ew[e] * dis[dst[e]];
}

// Wcat[k][j] (128x128): j<64 -> Wmu[k][j], else Wlv[k][j-64]
__global__ void concat_w(const float* __restrict__ Wmu, const float* __restrict__ Wlv,
                         float* __restrict__ wcat) {
    int i = blockIdx.x * 256 + threadIdx.x;  // 0..16383
    int k = i >> 7, j = i & 127;
    wcat[i] = (j < 64) ? Wmu[k * 64 + j] : Wlv[k * 64 + (j - 64)];
}

// ---------------- fp32 tiled GEMM: C[M,128] = A[M,K] @ B[K,128] ----------------
// BM=64, BN=128, BK=32, 256 threads, 32 outputs/thread (8m x 4n).
template <int K, bool RELU_A>
__global__ __launch_bounds__(256) void gemm128(const float* __restrict__ A,
                                               const float* __restrict__ B,
                                               float* __restrict__ C, int M) {
    constexpr int BM = 64, BN = 128, BK = 32;
    __shared__ float As[BK][BM + 4];  // As[k][m], row stride 68 floats (16B-aligned)
    __shared__ float Bs[BK][BN + 4];  // Bs[k][n], row stride 132 floats

    const int t = threadIdx.x;
    const int bm = blockIdx.x * BM;
    const int tmi = t >> 5;   // 0..7  -> rows tmi*8 .. +7
    const int tni = t & 31;   // 0..31 -> cols tni*4 .. +3

    // A staging: per pass 32 rows x 32 k; thread -> row t>>3, k-quad (t&7)*4
    const int ar = t >> 3;
    const int ak = (t & 7) * 4;
    // B staging: per pass 8 rows x 128 cols
    const int bkr = t >> 5;
    const int bc = (t & 31) * 4;

    float acc[8][4] = {};

    for (int k0 = 0; k0 < K; k0 += BK) {
#pragma unroll
        for (int p = 0; p < 2; ++p) {
            int row = bm + p * 32 + ar;
            float4 v = make_float4(0.f, 0.f, 0.f, 0.f);
            if (row < M) v = *reinterpret_cast<const float4*>(&A[(long)row * K + k0 + ak]);
            if (RELU_A) {
                v.x = fmaxf(v.x, 0.f); v.y = fmaxf(v.y, 0.f);
                v.z = fmaxf(v.z, 0.f); v.w = fmaxf(v.w, 0.f);
            }
            As[ak + 0][p * 32 + ar] = v.x;
            As[ak + 1][p * 32 + ar] = v.y;
            As[ak + 2][p * 32 + ar] = v.z;
            As[ak + 3][p * 32 + ar] = v.w;
        }
#pragma unroll
        for (int p = 0; p < 4; ++p) {
            int kr = p * 8 + bkr;
            float4 v = *reinterpret_cast<const float4*>(&B[(long)(k0 + kr) * BN + bc]);
            *reinterpret_cast<float4*>(&Bs[kr][bc]) = v;
        }
        __syncthreads();
#pragma unroll
        for (int k = 0; k < BK; ++k) {
            float4 a0 = *reinterpret_cast<const float4*>(&As[k][tmi * 8]);
            float4 a1 = *reinterpret_cast<const float4*>(&As[k][tmi * 8 + 4]);
            float4 bv = *reinterpret_cast<const float4*>(&Bs[k][tni * 4]);
            float a[8] = {a0.x, a0.y, a0.z, a0.w, a1.x, a1.y, a1.z, a1.w};
            float b[4] = {bv.x, bv.y, bv.z, bv.w};
#pragma unroll
            for (int i = 0; i < 8; ++i)
#pragma unroll
                for (int j = 0; j < 4; ++j) acc[i][j] += a[i] * b[j];
        }
        __syncthreads();
    }
#pragma unroll
    for (int i = 0; i < 8; ++i) {
        int row = bm + tmi * 8 + i;
        if (row < M) {
            float4 v = make_float4(acc[i][0], acc[i][1], acc[i][2], acc[i][3]);
            *reinterpret_cast<float4*>(&C[(long)row * BN + tni * 4]) = v;
        }
    }
}

// ---------------- conv init / scatter ----------------

// out[n][c] = hlin[n][c]*dis[n]^2 + bias[c]   (self-loop + bias, also overwrites poison)
__global__ void conv_init(const float* __restrict__ hlin, const float* __restrict__ dis,
                          const float* __restrict__ bias, float* __restrict__ out) {
    int tid = blockIdx.x * 256 + threadIdx.x;  // N_NODES*32
    int n = tid >> 5, q = tid & 31;
    float d = dis[n];
    float s = d * d;
    float4 v = *reinterpret_cast<const float4*>(&hlin[(long)n * 128 + q * 4]);
    float4 b = *reinterpret_cast<const float4*>(&bias[q * 4]);
    float4 o = make_float4(v.x * s + b.x, v.y * s + b.y, v.z * s + b.z, v.w * s + b.w);
    *reinterpret_cast<float4*>(&out[(long)n * 128 + q * 4]) = o;
}

__global__ void conv_scatter(const int* __restrict__ src, const int* __restrict__ dst,
                             const float* __restrict__ norm, const float* __restrict__ msg,
                             float* __restrict__ out) {
    long tid = (long)blockIdx.x * 256 + threadIdx.x;  // N_EDGES*32
    int e = (int)(tid >> 5), q = (int)(tid & 31);
    float w = norm[e];
    int s = src[e], d = dst[e];
    float4 v = *reinterpret_cast<const float4*>(&msg[(long)s * 128 + q * 4]);
    float* p = &out[(long)d * 128 + q * 4];
    unsafeAtomicAdd(p + 0, v.x * w);
    unsafeAtomicAdd(p + 1, v.y * w);
    unsafeAtomicAdd(p + 2, v.z * w);
    unsafeAtomicAdd(p + 3, v.w * w);
}

// second conv: g[n][0:64] -> mu, g[n][64:128] -> logvar
__global__ void conv_init2(const float* __restrict__ g, const float* __restrict__ dis,
                           const float* __restrict__ bmu, const float* __restrict__ blv,
                           float* __restrict__ outmu, float* __restrict__ outlv) {
    int tid = blockIdx.x * 256 + threadIdx.x;  // N_NODES*32
    int n = tid >> 5, q = tid & 31;
    float d = dis[n];
    float s = d * d;
    float4 v = *reinterpret_cast<const float4*>(&g[(long)n * 128 + q * 4]);
    float4 b;
    float* outp;
    if (q < 16) {
        b = *reinterpret_cast<const float4*>(&bmu[q * 4]);
        outp = &outmu[(long)n * 64 + q * 4];
    } else {
        b = *reinterpret_cast<const float4*>(&blv[(q - 16) * 4]);
        outp = &outlv[(long)n * 64 + (q - 16) * 4];
    }
    float4 o = make_float4(v.x * s + b.x, v.y * s + b.y, v.z * s + b.z, v.w * s + b.w);
    *reinterpret_cast<float4*>(outp) = o;
}

__global__ void conv_scatter2(const int* __restrict__ src, const int* __restrict__ dst,
                              const float* __restrict__ norm, const float* __restrict__ g,
                              float* __restrict__ outmu, float* __restrict__ outlv) {
    long tid = (long)blockIdx.x * 256 + threadIdx.x;  // N_EDGES*32
    int e = (int)(tid >> 5), q = (int)(tid & 31);
    float w = norm[e];
    int s = src[e], d = dst[e];
    float4 v = *reinterpret_cast<const float4*>(&g[(long)s * 128 + q * 4]);
    float* p = (q < 16) ? &outmu[(long)d * 64 + q * 4] : &outlv[(long)d * 64 + (q - 16) * 4];
    unsafeAtomicAdd(p + 0, v.x * w);
    unsafeAtomicAdd(p + 1, v.y * w);
    unsafeAtomicAdd(p + 2, v.z * w);
    unsafeAtomicAdd(p + 3, v.w * w);
}

// ---------------- launch ----------------

extern "C" void kernel_launch(void* const* d_in, const int* in_sizes, int n_in,
                              void* d_out, int out_size, void* d_ws, size_t ws_size,
                              hipStream_t stream) {
    const float* x   = (const float*)d_in[0];
    const int*   ei  = (const int*)d_in[1];
    const float* ew  = (const float*)d_in[2];
    const float* W1  = (const float*)d_in[3];
    const float* b1  = (const float*)d_in[4];
    const float* Wmu = (const float*)d_in[5];
    const float* bmu = (const float*)d_in[6];
    const float* Wlv = (const float*)d_in[7];
    const float* blv = (const float*)d_in[8];

    const int* srcI = ei;            // edge_index[0]
    const int* dstI = ei + N_EDGES;  // edge_index[1]

    float* ws = (float*)d_ws;
    float* deg  = ws;              // 100000 (becomes dis in place)
    float* nrm  = ws + 100352;     // 1600000
    float* wcat = ws + 1700352;    // 16384
    float* hlin = ws + 1716736;    // 12.8M
    float* h    = ws + 14516736;   // 12.8M
    float* g    = hlin;            // reuse: hlin dead after conv_scatter1
    float* outmu = (float*)d_out;
    float* outlv = outmu + (long)N_NODES * 64;

    zero_f32<<<(N_NODES + 255) / 256, 256, 0, stream>>>(deg, N_NODES);
    scatter_deg<<<N_EDGES / 256, 256, 0, stream>>>(dstI, ew, deg);
    compute_dis<<<(N_NODES + 255) / 256, 256, 0, stream>>>(deg);
    compute_norm<<<N_EDGES / 256, 256, 0, stream>>>(srcI, dstI, ew, deg, nrm);
    concat_w<<<64, 256, 0, stream>>>(Wmu, Wlv, wcat);

    gemm128<256, false><<<(N_NODES + 63) / 64, 256, 0, stream>>>(x, W1, hlin, N_NODES);
    conv_init<<<N_NODES * 32 / 256, 256, 0, stream>>>(hlin, deg, b1, h);
    conv_scatter<<<N_EDGES * 32 / 256, 256, 0, stream>>>(srcI, dstI, nrm, hlin, h);

    gemm128<128, true><<<(N_NODES + 63) / 64, 256, 0, stream>>>(h, wcat, g, N_NODES);
    conv_init2<<<N_NODES * 32 / 256, 256, 0, stream>>>(g, deg, bmu, blv, outmu, outlv);
    conv_scatter2<<<N_EDGES * 32 / 256, 256, 0, stream>>>(srcI, dstI, nrm, g, outmu, outlv);
}

// Round 2
// 790.476 us; speedup vs baseline: 7.3028x; 7.3028x over previous
//
#include <hip/hip_runtime.h>
#include <hip/hip_bf16.h>

#define N_NODES 100000
#define N_EDGES 1600000
// IN_CH=256, HID_CH=128, OUT_CH=64

// ---------------- utility ----------------

__global__ void zero_f32(float* __restrict__ p, int n) {
    int i = blockIdx.x * 256 + threadIdx.x;
    if (i < n) p[i] = 0.0f;
}

__global__ void zero_i32(int* __restrict__ p, int n) {
    int i = blockIdx.x * 256 + threadIdx.x;
    if (i < n) p[i] = 0;
}

// ---------------- gcn_norm ----------------

__global__ void scatter_deg(const int* __restrict__ dst, const float* __restrict__ ew,
                            float* __restrict__ deg) {
    int e = blockIdx.x * 256 + threadIdx.x;
    if (e < N_EDGES) unsafeAtomicAdd(&deg[dst[e]], ew[e]);
}

// deg -> dis in place. Self-loop adds weight 1 to every node, so deg+1 >= 1.
__global__ void compute_dis(float* __restrict__ deg) {
    int n = blockIdx.x * 256 + threadIdx.x;
    if (n < N_NODES) deg[n] = rsqrtf(deg[n] + 1.0f);
}

// ---------------- CSR build (by dst) ----------------

__global__ void csr_count(const int* __restrict__ dst, int* __restrict__ cnt) {
    int e = blockIdx.x * 256 + threadIdx.x;
    if (e < N_EDGES) atomicAdd(&cnt[dst[e]], 1);
}

// block-local exclusive scan of cnt into rowptr, block sums to bsum
__global__ __launch_bounds__(256) void scan1(const int* __restrict__ cnt,
                                             int* __restrict__ rowptr,
                                             int* __restrict__ bsum) {
    __shared__ int s[256];
    int tid = threadIdx.x;
    int i = blockIdx.x * 256 + tid;
    int v = (i < N_NODES) ? cnt[i] : 0;
    s[tid] = v;
    __syncthreads();
#pragma unroll
    for (int off = 1; off < 256; off <<= 1) {
        int t = (tid >= off) ? s[tid - off] : 0;
        __syncthreads();
        s[tid] += t;
        __syncthreads();
    }
    if (i < N_NODES) rowptr[i] = s[tid] - v;  // exclusive
    if (tid == 255) bsum[blockIdx.x] = s[255];
}

// scan 391 block sums (one block, 512 threads), exclusive, in place
__global__ __launch_bounds__(512) void scan2(int* __restrict__ bsum, int nb) {
    __shared__ int s[512];
    int tid = threadIdx.x;
    int v = (tid < nb) ? bsum[tid] : 0;
    s[tid] = v;
    __syncthreads();
#pragma unroll
    for (int off = 1; off < 512; off <<= 1) {
        int t = (tid >= off) ? s[tid - off] : 0;
        __syncthreads();
        s[tid] += t;
        __syncthreads();
    }
    if (tid < nb) bsum[tid] = s[tid] - v;  // exclusive
}

__global__ void scan3(int* __restrict__ rowptr, const int* __restrict__ bsum) {
    int i = blockIdx.x * 256 + threadIdx.x;
    if (i < N_NODES) rowptr[i] += bsum[blockIdx.x];
    if (i == 0) rowptr[N_NODES] = N_EDGES;
}

// fill CSR: esrc/enorm sorted by dst; norm computed inline (fuses compute_norm)
__global__ void csr_fill(const int* __restrict__ src, const int* __restrict__ dst,
                         const float* __restrict__ ew, const float* __restrict__ dis,
                         const int* __restrict__ rowptr, int* __restrict__ cursor,
                         int* __restrict__ esrc, float* __restrict__ enorm) {
    int e = blockIdx.x * 256 + threadIdx.x;
    if (e >= N_EDGES) return;
    int s = src[e], d = dst[e];
    float w = dis[s] * ew[e] * dis[d];
    int idx = rowptr[d] + atomicAdd(&cursor[d], 1);
    esrc[idx] = s;
    enorm[idx] = w;
}

// Wcat[k][j] (128x128): j<64 -> Wmu[k][j], else Wlv[k][j-64]
__global__ void concat_w(const float* __restrict__ Wmu, const float* __restrict__ Wlv,
                         float* __restrict__ wcat) {
    int i = blockIdx.x * 256 + threadIdx.x;  // 0..16383
    int k = i >> 7, j = i & 127;
    wcat[i] = (j < 64) ? Wmu[k * 64 + j] : Wlv[k * 64 + (j - 64)];
}

// ---------------- fp32 tiled GEMM: C[M,128] = A[M,K] @ B[K,128] ----------------
template <int K, bool RELU_A>
__global__ __launch_bounds__(256) void gemm128(const float* __restrict__ A,
                                               const float* __restrict__ B,
                                               float* __restrict__ C, int M) {
    constexpr int BM = 64, BN = 128, BK = 32;
    __shared__ float As[BK][BM + 4];
    __shared__ float Bs[BK][BN + 4];

    const int t = threadIdx.x;
    const int bm = blockIdx.x * BM;
    const int tmi = t >> 5;
    const int tni = t & 31;
    const int ar = t >> 3;
    const int ak = (t & 7) * 4;
    const int bkr = t >> 5;
    const int bc = (t & 31) * 4;

    float acc[8][4] = {};

    for (int k0 = 0; k0 < K; k0 += BK) {
#pragma unroll
        for (int p = 0; p < 2; ++p) {
            int row = bm + p * 32 + ar;
            float4 v = make_float4(0.f, 0.f, 0.f, 0.f);
            if (row < M) v = *reinterpret_cast<const float4*>(&A[(long)row * K + k0 + ak]);
            if (RELU_A) {
                v.x = fmaxf(v.x, 0.f); v.y = fmaxf(v.y, 0.f);
                v.z = fmaxf(v.z, 0.f); v.w = fmaxf(v.w, 0.f);
            }
            As[ak + 0][p * 32 + ar] = v.x;
            As[ak + 1][p * 32 + ar] = v.y;
            As[ak + 2][p * 32 + ar] = v.z;
            As[ak + 3][p * 32 + ar] = v.w;
        }
#pragma unroll
        for (int p = 0; p < 4; ++p) {
            int kr = p * 8 + bkr;
            float4 v = *reinterpret_cast<const float4*>(&B[(long)(k0 + kr) * BN + bc]);
            *reinterpret_cast<float4*>(&Bs[kr][bc]) = v;
        }
        __syncthreads();
#pragma unroll
        for (int k = 0; k < BK; ++k) {
            float4 a0 = *reinterpret_cast<const float4*>(&As[k][tmi * 8]);
            float4 a1 = *reinterpret_cast<const float4*>(&As[k][tmi * 8 + 4]);
            float4 bv = *reinterpret_cast<const float4*>(&Bs[k][tni * 4]);
            float a[8] = {a0.x, a0.y, a0.z, a0.w, a1.x, a1.y, a1.z, a1.w};
            float b[4] = {bv.x, bv.y, bv.z, bv.w};
#pragma unroll
            for (int i = 0; i < 8; ++i)
#pragma unroll
                for (int j = 0; j < 4; ++j) acc[i][j] += a[i] * b[j];
        }
        __syncthreads();
    }
#pragma unroll
    for (int i = 0; i < 8; ++i) {
        int row = bm + tmi * 8 + i;
        if (row < M) {
            float4 v = make_float4(acc[i][0], acc[i][1], acc[i][2], acc[i][3]);
            *reinterpret_cast<float4*>(&C[(long)row * BN + tni * 4]) = v;
        }
    }
}

// ---------------- gather-reduce convs (no atomics) ----------------
// 32 lanes per node, float4 per lane covers 128 channels.
// acc init = self-loop (hlin[n]*dis[n]^2) + bias; then walk in-edges.

__global__ __launch_bounds__(256) void gather_conv1(
    const int* __restrict__ rowptr, const int* __restrict__ esrc,
    const float* __restrict__ enorm, const float* __restrict__ hlin,
    const float* __restrict__ dis, const float* __restrict__ bias,
    float* __restrict__ out) {
    int tid = blockIdx.x * 256 + threadIdx.x;  // N_NODES*32
    int n = tid >> 5, q = tid & 31;
    float dv = dis[n];
    float s2 = dv * dv;
    float4 b = *reinterpret_cast<const float4*>(&bias[q * 4]);
    float4 sv = *reinterpret_cast<const float4*>(&hlin[(long)n * 128 + q * 4]);
    float ax = sv.x * s2 + b.x, ay = sv.y * s2 + b.y;
    float az = sv.z * s2 + b.z, aw = sv.w * s2 + b.w;

    int j = rowptr[n], end = rowptr[n + 1];
    for (; j + 2 <= end; j += 2) {
        int s0 = esrc[j], s1 = esrc[j + 1];
        float w0 = enorm[j], w1 = enorm[j + 1];
        float4 m0 = *reinterpret_cast<const float4*>(&hlin[(long)s0 * 128 + q * 4]);
        float4 m1 = *reinterpret_cast<const float4*>(&hlin[(long)s1 * 128 + q * 4]);
        ax += m0.x * w0 + m1.x * w1;
        ay += m0.y * w0 + m1.y * w1;
        az += m0.z * w0 + m1.z * w1;
        aw += m0.w * w0 + m1.w * w1;
    }
    if (j < end) {
        int s0 = esrc[j];
        float w0 = enorm[j];
        float4 m0 = *reinterpret_cast<const float4*>(&hlin[(long)s0 * 128 + q * 4]);
        ax += m0.x * w0; ay += m0.y * w0; az += m0.z * w0; aw += m0.w * w0;
    }
    *reinterpret_cast<float4*>(&out[(long)n * 128 + q * 4]) =
        make_float4(ax, ay, az, aw);
}

// conv2: g[n][0:64] -> mu, g[n][64:128] -> logvar
__global__ __launch_bounds__(256) void gather_conv2(
    const int* __restrict__ rowptr, const int* __restrict__ esrc,
    const float* __restrict__ enorm, const float* __restrict__ g,
    const float* __restrict__ dis, const float* __restrict__ bmu,
    const float* __restrict__ blv, float* __restrict__ outmu,
    float* __restrict__ outlv) {
    int tid = blockIdx.x * 256 + threadIdx.x;  // N_NODES*32
    int n = tid >> 5, q = tid & 31;
    float dv = dis[n];
    float s2 = dv * dv;
    float4 b = (q < 16) ? *reinterpret_cast<const float4*>(&bmu[q * 4])
                        : *reinterpret_cast<const float4*>(&blv[(q - 16) * 4]);
    float4 sv = *reinterpret_cast<const float4*>(&g[(long)n * 128 + q * 4]);
    float ax = sv.x * s2 + b.x, ay = sv.y * s2 + b.y;
    float az = sv.z * s2 + b.z, aw = sv.w * s2 + b.w;

    int j = rowptr[n], end = rowptr[n + 1];
    for (; j + 2 <= end; j += 2) {
        int s0 = esrc[j], s1 = esrc[j + 1];
        float w0 = enorm[j], w1 = enorm[j + 1];
        float4 m0 = *reinterpret_cast<const float4*>(&g[(long)s0 * 128 + q * 4]);
        float4 m1 = *reinterpret_cast<const float4*>(&g[(long)s1 * 128 + q * 4]);
        ax += m0.x * w0 + m1.x * w1;
        ay += m0.y * w0 + m1.y * w1;
        az += m0.z * w0 + m1.z * w1;
        aw += m0.w * w0 + m1.w * w1;
    }
    if (j < end) {
        int s0 = esrc[j];
        float w0 = enorm[j];
        float4 m0 = *reinterpret_cast<const float4*>(&g[(long)s0 * 128 + q * 4]);
        ax += m0.x * w0; ay += m0.y * w0; az += m0.z * w0; aw += m0.w * w0;
    }
    float4 o = make_float4(ax, ay, az, aw);
    if (q < 16)
        *reinterpret_cast<float4*>(&outmu[(long)n * 64 + q * 4]) = o;
    else
        *reinterpret_cast<float4*>(&outlv[(long)n * 64 + (q - 16) * 4]) = o;
}

// ---------------- launch ----------------

extern "C" void kernel_launch(void* const* d_in, const int* in_sizes, int n_in,
                              void* d_out, int out_size, void* d_ws, size_t ws_size,
                              hipStream_t stream) {
    const float* x   = (const float*)d_in[0];
    const int*   ei  = (const int*)d_in[1];
    const float* ew  = (const float*)d_in[2];
    const float* W1  = (const float*)d_in[3];
    const float* b1  = (const float*)d_in[4];
    const float* Wmu = (const float*)d_in[5];
    const float* bmu = (const float*)d_in[6];
    const float* Wlv = (const float*)d_in[7];
    const float* blv = (const float*)d_in[8];

    const int* srcI = ei;            // edge_index[0]
    const int* dstI = ei + N_EDGES;  // edge_index[1]

    float* ws = (float*)d_ws;
    // layout (floats):
    float* dis    = ws;                        // 100352
    float* wcat   = ws + 100352;               // 16384
    float* enorm  = ws + 116736;               // 1600000
    int*   esrc   = (int*)(ws + 1716736);      // 1600000
    int*   cnt    = (int*)(ws + 3316736);      // 100352 (count, then cursor)
    int*   rowptr = (int*)(ws + 3417088);      // 100352 (needs 100001)
    int*   bsum   = (int*)(ws + 3517440);      // 512
    float* hlin   = ws + 3517952;              // 12800000
    float* h      = ws + 16317952;             // 12800000 (ends 29117952 ~ 116.5 MB)
    float* g      = hlin;                      // reuse: hlin dead after gather_conv1
    float* outmu  = (float*)d_out;
    float* outlv  = outmu + (long)N_NODES * 64;

    const int NB = (N_NODES + 255) / 256;  // 391

    // degree / dis
    zero_f32<<<NB, 256, 0, stream>>>(dis, N_NODES);
    scatter_deg<<<N_EDGES / 256, 256, 0, stream>>>(dstI, ew, dis);
    compute_dis<<<NB, 256, 0, stream>>>(dis);

    // CSR by dst
    zero_i32<<<NB, 256, 0, stream>>>(cnt, N_NODES);
    csr_count<<<N_EDGES / 256, 256, 0, stream>>>(dstI, cnt);
    scan1<<<NB, 256, 0, stream>>>(cnt, rowptr, bsum);
    scan2<<<1, 512, 0, stream>>>(bsum, NB);
    scan3<<<NB, 256, 0, stream>>>(rowptr, bsum);
    zero_i32<<<NB, 256, 0, stream>>>(cnt, N_NODES);  // cursor
    csr_fill<<<N_EDGES / 256, 256, 0, stream>>>(srcI, dstI, ew, dis, rowptr, cnt,
                                                esrc, enorm);

    concat_w<<<64, 256, 0, stream>>>(Wmu, Wlv, wcat);

    // layer 1
    gemm128<256, false><<<(N_NODES + 63) / 64, 256, 0, stream>>>(x, W1, hlin, N_NODES);
    gather_conv1<<<N_NODES * 32 / 256, 256, 0, stream>>>(rowptr, esrc, enorm, hlin,
                                                         dis, b1, h);
    // layer 2 (mu | logvar fused)
    gemm128<128, true><<<(N_NODES + 63) / 64, 256, 0, stream>>>(h, wcat, g, N_NODES);
    gather_conv2<<<N_NODES * 32 / 256, 256, 0, stream>>>(rowptr, esrc, enorm, g, dis,
                                                         bmu, blv, outmu, outlv);
}

// Round 4
// 633.222 us; speedup vs baseline: 9.1164x; 1.2483x over previous
//
#include <hip/hip_runtime.h>
#include <hip/hip_bf16.h>

#define N_NODES 100000
#define N_EDGES 1600000
// IN_CH=256, HID_CH=128, OUT_CH=64

typedef __attribute__((ext_vector_type(8))) short short8;
typedef __attribute__((ext_vector_type(8))) unsigned short u16x8;
typedef __attribute__((ext_vector_type(4))) unsigned short u16x4;
typedef __attribute__((ext_vector_type(4))) float f32x4;

__device__ __forceinline__ unsigned short f2bf(float f) {
    union { float f; unsigned u; } v;
    v.f = f;
    unsigned r = v.u + 0x7FFFu + ((v.u >> 16) & 1u);  // RNE
    return (unsigned short)(r >> 16);
}
__device__ __forceinline__ float bf2f(unsigned short u) {
    union { unsigned u; float f; } v;
    v.u = (unsigned)u << 16;
    return v.f;
}

// ---------------- gcn_norm + CSR build ----------------

__global__ void deg_count(const int* __restrict__ dst, const float* __restrict__ ew,
                          float* __restrict__ deg, int* __restrict__ cnt) {
    int e = blockIdx.x * 256 + threadIdx.x;
    if (e < N_EDGES) {
        int d = dst[e];
        unsafeAtomicAdd(&deg[d], ew[e]);
        atomicAdd(&cnt[d], 1);
    }
}

// deg -> dis in place (self-loop adds 1)
__global__ void compute_dis(float* __restrict__ deg) {
    int n = blockIdx.x * 256 + threadIdx.x;
    if (n < N_NODES) deg[n] = rsqrtf(deg[n] + 1.0f);
}

__global__ __launch_bounds__(256) void scan1(const int* __restrict__ cnt,
                                             int* __restrict__ rowptr,
                                             int* __restrict__ bsum) {
    __shared__ int s[256];
    int tid = threadIdx.x;
    int i = blockIdx.x * 256 + tid;
    int v = (i < N_NODES) ? cnt[i] : 0;
    s[tid] = v;
    __syncthreads();
#pragma unroll
    for (int off = 1; off < 256; off <<= 1) {
        int t = (tid >= off) ? s[tid - off] : 0;
        __syncthreads();
        s[tid] += t;
        __syncthreads();
    }
    if (i < N_NODES) rowptr[i] = s[tid] - v;  // exclusive
    if (tid == 255) bsum[blockIdx.x] = s[255];
}

__global__ __launch_bounds__(512) void scan2(int* __restrict__ bsum, int nb) {
    __shared__ int s[512];
    int tid = threadIdx.x;
    int v = (tid < nb) ? bsum[tid] : 0;
    s[tid] = v;
    __syncthreads();
#pragma unroll
    for (int off = 1; off < 512; off <<= 1) {
        int t = (tid >= off) ? s[tid - off] : 0;
        __syncthreads();
        s[tid] += t;
        __syncthreads();
    }
    if (tid < nb) bsum[tid] = s[tid] - v;  // exclusive
}

__global__ void scan3(int* __restrict__ rowptr, const int* __restrict__ bsum) {
    int i = blockIdx.x * 256 + threadIdx.x;
    if (i < N_NODES) rowptr[i] += bsum[blockIdx.x];
    if (i == 0) rowptr[N_NODES] = N_EDGES;
}

__global__ void csr_fill(const int* __restrict__ src, const int* __restrict__ dst,
                         const float* __restrict__ ew, const float* __restrict__ dis,
                         const int* __restrict__ rowptr, int* __restrict__ cursor,
                         int* __restrict__ esrc, float* __restrict__ enorm) {
    int e = blockIdx.x * 256 + threadIdx.x;
    if (e >= N_EDGES) return;
    int s = src[e], d = dst[e];
    float w = dis[s] * ew[e] * dis[d];
    int idx = rowptr[d] + atomicAdd(&cursor[d], 1);
    esrc[idx] = s;
    enorm[idx] = w;
}

// ---------------- weight prep: transpose + bf16 ----------------

// W1T[n][k] = bf16(W1[k][n]); W1: 256x128
__global__ void w1_trans(const float* __restrict__ W, unsigned short* __restrict__ WT) {
    int i = blockIdx.x * 256 + threadIdx.x;  // 32768
    int k = i >> 7, n = i & 127;
    WT[n * 256 + k] = f2bf(W[i]);
}

// WcatT[n][k] (128x128): n<64 -> Wmu[k][n], else Wlv[k][n-64]
__global__ void wcat_trans(const float* __restrict__ Wmu, const float* __restrict__ Wlv,
                           unsigned short* __restrict__ WT) {
    int i = blockIdx.x * 256 + threadIdx.x;  // 16384
    int n = i >> 7, k = i & 127;
    float v = (n < 64) ? Wmu[k * 64 + n] : Wlv[k * 64 + (n - 64)];
    WT[n * 128 + k] = f2bf(v);
}

// ---------------- bf16 MFMA GEMM: C[M,128] = A[M,K] @ WT^T ----------------
// WT is [128][K] bf16 (pre-transposed). BM=64 (4 waves x 16 rows), BN=128, BK=32.
// As[kb][row][8] = A[bm+row][k0+kb*8+j]; Bs[kb][n][8] = WT[n][k0+kb*8+j].
// a_frag: row = lane&15 (+wave*16), k = 8*(lane>>4)+j.
// b_frag: n = lane&15 (+f*16),      k = 8*(lane>>4)+j.
// C/D:    col = lane&15, row = (lane>>4)*4 + reg  [m89 verified].
template <int K, bool A_BF16>
__global__ __launch_bounds__(256) void gemm_mfma(const void* __restrict__ Aptr,
                                                 const unsigned short* __restrict__ WT,
                                                 unsigned short* __restrict__ C, int M) {
    __shared__ unsigned short As[4 * 64 * 8];   // 4 KB
    __shared__ unsigned short Bs[4 * 128 * 8];  // 8 KB
    const int t = threadIdx.x;
    const int wave = t >> 6, lane = t & 63;
    const int l15 = lane & 15, l4 = lane >> 4;
    const int bm = blockIdx.x * 64;

    f32x4 acc[8] = {};

    const int ar = t >> 2;   // A staging row 0..63
    const int akb = t & 3;   // A staging k-block
    const int bn = t >> 1;   // B staging n 0..127

    for (int k0 = 0; k0 < K; k0 += 32) {
        {
            int row = bm + ar;
            u16x8 av = {};
            if (row < M) {
                if (A_BF16) {
                    av = *reinterpret_cast<const u16x8*>(
                        &((const unsigned short*)Aptr)[(long)row * K + k0 + akb * 8]);
                } else {
                    const float* Af = (const float*)Aptr;
                    float4 v0 = *reinterpret_cast<const float4*>(&Af[(long)row * K + k0 + akb * 8]);
                    float4 v1 = *reinterpret_cast<const float4*>(&Af[(long)row * K + k0 + akb * 8 + 4]);
                    av[0] = f2bf(v0.x); av[1] = f2bf(v0.y); av[2] = f2bf(v0.z); av[3] = f2bf(v0.w);
                    av[4] = f2bf(v1.x); av[5] = f2bf(v1.y); av[6] = f2bf(v1.z); av[7] = f2bf(v1.w);
                }
            }
            *reinterpret_cast<u16x8*>(&As[(akb * 64 + ar) * 8]) = av;
        }
#pragma unroll
        for (int c = 0; c < 2; ++c) {
            int kb = (t & 1) * 2 + c;
            u16x8 bv = *reinterpret_cast<const u16x8*>(&WT[(long)bn * K + k0 + kb * 8]);
            *reinterpret_cast<u16x8*>(&Bs[(kb * 128 + bn) * 8]) = bv;
        }
        __syncthreads();
        short8 a = *reinterpret_cast<const short8*>(&As[(l4 * 64 + wave * 16 + l15) * 8]);
#pragma unroll
        for (int f = 0; f < 8; ++f) {
            short8 b = *reinterpret_cast<const short8*>(&Bs[(l4 * 128 + f * 16 + l15) * 8]);
            acc[f] = __builtin_amdgcn_mfma_f32_16x16x32_bf16(a, b, acc[f], 0, 0, 0);
        }
        __syncthreads();
    }
#pragma unroll
    for (int f = 0; f < 8; ++f) {
#pragma unroll
        for (int r = 0; r < 4; ++r) {
            int row = bm + wave * 16 + l4 * 4 + r;
            if (row < M) C[(long)row * 128 + f * 16 + l15] = f2bf(acc[f][r]);
        }
    }
}

// ---------------- gather-reduce convs (bf16 messages, f32 accum) ----------------
// 32 lanes per node, 4 channels (8 B) per lane.

__global__ __launch_bounds__(256) void gather_conv1(
    const int* __restrict__ rowptr, const int* __restrict__ esrc,
    const float* __restrict__ enorm, const unsigned short* __restrict__ hlin,
    const float* __restrict__ dis, const float* __restrict__ bias,
    unsigned short* __restrict__ hout) {
    int tid = blockIdx.x * 256 + threadIdx.x;  // N_NODES*32
    int n = tid >> 5, q = tid & 31;
    float dv = dis[n], s2 = dv * dv;
    float4 b = *reinterpret_cast<const float4*>(&bias[q * 4]);
    u16x4 sv = *reinterpret_cast<const u16x4*>(&hlin[(long)n * 128 + q * 4]);
    float a0 = bf2f(sv[0]) * s2 + b.x;
    float a1 = bf2f(sv[1]) * s2 + b.y;
    float a2 = bf2f(sv[2]) * s2 + b.z;
    float a3 = bf2f(sv[3]) * s2 + b.w;

    int j = rowptr[n], end = rowptr[n + 1];
    for (; j + 2 <= end; j += 2) {
        int s0 = esrc[j], s1 = esrc[j + 1];
        float w0 = enorm[j], w1 = enorm[j + 1];
        u16x4 m0 = *reinterpret_cast<const u16x4*>(&hlin[(long)s0 * 128 + q * 4]);
        u16x4 m1 = *reinterpret_cast<const u16x4*>(&hlin[(long)s1 * 128 + q * 4]);
        a0 += bf2f(m0[0]) * w0 + bf2f(m1[0]) * w1;
        a1 += bf2f(m0[1]) * w0 + bf2f(m1[1]) * w1;
        a2 += bf2f(m0[2]) * w0 + bf2f(m1[2]) * w1;
        a3 += bf2f(m0[3]) * w0 + bf2f(m1[3]) * w1;
    }
    if (j < end) {
        int s0 = esrc[j];
        float w0 = enorm[j];
        u16x4 m0 = *reinterpret_cast<const u16x4*>(&hlin[(long)s0 * 128 + q * 4]);
        a0 += bf2f(m0[0]) * w0; a1 += bf2f(m0[1]) * w0;
        a2 += bf2f(m0[2]) * w0; a3 += bf2f(m0[3]) * w0;
    }
    // fused ReLU + bf16 pack (feeds GEMM2 directly)
    u16x4 o;
    o[0] = f2bf(fmaxf(a0, 0.f)); o[1] = f2bf(fmaxf(a1, 0.f));
    o[2] = f2bf(fmaxf(a2, 0.f)); o[3] = f2bf(fmaxf(a3, 0.f));
    *reinterpret_cast<u16x4*>(&hout[(long)n * 128 + q * 4]) = o;
}

// conv2: g[n][0:64] -> mu, g[n][64:128] -> logvar (f32 outputs)
__global__ __launch_bounds__(256) void gather_conv2(
    const int* __restrict__ rowptr, const int* __restrict__ esrc,
    const float* __restrict__ enorm, const unsigned short* __restrict__ g,
    const float* __restrict__ dis, const float* __restrict__ bmu,
    const float* __restrict__ blv, float* __restrict__ outmu,
    float* __restrict__ outlv) {
    int tid = blockIdx.x * 256 + threadIdx.x;  // N_NODES*32
    int n = tid >> 5, q = tid & 31;
    float dv = dis[n], s2 = dv * dv;
    float4 b = (q < 16) ? *reinterpret_cast<const float4*>(&bmu[q * 4])
                        : *reinterpret_cast<const float4*>(&blv[(q - 16) * 4]);
    u16x4 sv = *reinterpret_cast<const u16x4*>(&g[(long)n * 128 + q * 4]);
    float a0 = bf2f(sv[0]) * s2 + b.x;
    float a1 = bf2f(sv[1]) * s2 + b.y;
    float a2 = bf2f(sv[2]) * s2 + b.z;
    float a3 = bf2f(sv[3]) * s2 + b.w;

    int j = rowptr[n], end = rowptr[n + 1];
    for (; j + 2 <= end; j += 2) {
        int s0 = esrc[j], s1 = esrc[j + 1];
        float w0 = enorm[j], w1 = enorm[j + 1];
        u16x4 m0 = *reinterpret_cast<const u16x4*>(&g[(long)s0 * 128 + q * 4]);
        u16x4 m1 = *reinterpret_cast<const u16x4*>(&g[(long)s1 * 128 + q * 4]);
        a0 += bf2f(m0[0]) * w0 + bf2f(m1[0]) * w1;
        a1 += bf2f(m0[1]) * w0 + bf2f(m1[1]) * w1;
        a2 += bf2f(m0[2]) * w0 + bf2f(m1[2]) * w1;
        a3 += bf2f(m0[3]) * w0 + bf2f(m1[3]) * w1;
    }
    if (j < end) {
        int s0 = esrc[j];
        float w0 = enorm[j];
        u16x4 m0 = *reinterpret_cast<const u16x4*>(&g[(long)s0 * 128 + q * 4]);
        a0 += bf2f(m0[0]) * w0; a1 += bf2f(m0[1]) * w0;
        a2 += bf2f(m0[2]) * w0; a3 += bf2f(m0[3]) * w0;
    }
    float4 o = make_float4(a0, a1, a2, a3);
    if (q < 16)
        *reinterpret_cast<float4*>(&outmu[(long)n * 64 + q * 4]) = o;
    else
        *reinterpret_cast<float4*>(&outlv[(long)n * 64 + (q - 16) * 4]) = o;
}

// ---------------- launch ----------------

extern "C" void kernel_launch(void* const* d_in, const int* in_sizes, int n_in,
                              void* d_out, int out_size, void* d_ws, size_t ws_size,
                              hipStream_t stream) {
    const float* x   = (const float*)d_in[0];
    const int*   ei  = (const int*)d_in[1];
    const float* ew  = (const float*)d_in[2];
    const float* W1  = (const float*)d_in[3];
    const float* b1  = (const float*)d_in[4];
    const float* Wmu = (const float*)d_in[5];
    const float* bmu = (const float*)d_in[6];
    const float* Wlv = (const float*)d_in[7];
    const float* blv = (const float*)d_in[8];

    const int* srcI = ei;            // edge_index[0]
    const int* dstI = ei + N_EDGES;  // edge_index[1]

    float* ws = (float*)d_ws;
    float*          dis    = ws;                               // 100352
    float*          enorm  = ws + 100352;                      // 1600000
    int*            esrc   = (int*)(ws + 1700352);             // 1600000
    int*            cnt    = (int*)(ws + 3300352);             // 100352
    int*            rowptr = (int*)(ws + 3400704);             // 100352 (needs 100001)
    int*            bsum   = (int*)(ws + 3501056);             // 512
    unsigned short* w1T    = (unsigned short*)(ws + 3501568);  // 32768 ush
    unsigned short* wcatT  = (unsigned short*)(ws + 3517952);  // 16384 ush
    unsigned short* hlin   = (unsigned short*)(ws + 3526144);  // 12.8M ush
    unsigned short* h      = (unsigned short*)(ws + 9926144);  // 12.8M ush (ends ~65 MB)
    unsigned short* g      = hlin;  // reuse: hlin dead after gather_conv1
    float* outmu = (float*)d_out;
    float* outlv = outmu + (long)N_NODES * 64;

    const int NB = (N_NODES + 255) / 256;  // 391
    const int EB = N_EDGES / 256;          // 6250

    hipMemsetAsync(dis, 0, N_NODES * sizeof(float), stream);
    hipMemsetAsync(cnt, 0, N_NODES * sizeof(int), stream);

    deg_count<<<EB, 256, 0, stream>>>(dstI, ew, dis, cnt);
    compute_dis<<<NB, 256, 0, stream>>>(dis);

    scan1<<<NB, 256, 0, stream>>>(cnt, rowptr, bsum);
    scan2<<<1, 512, 0, stream>>>(bsum, NB);
    scan3<<<NB, 256, 0, stream>>>(rowptr, bsum);
    hipMemsetAsync(cnt, 0, N_NODES * sizeof(int), stream);  // cursor
    csr_fill<<<EB, 256, 0, stream>>>(srcI, dstI, ew, dis, rowptr, cnt, esrc, enorm);

    w1_trans<<<128, 256, 0, stream>>>(W1, w1T);
    wcat_trans<<<64, 256, 0, stream>>>(Wmu, Wlv, wcatT);

    // layer 1
    gemm_mfma<256, false><<<(N_NODES + 63) / 64, 256, 0, stream>>>(x, w1T, hlin, N_NODES);
    gather_conv1<<<N_NODES * 32 / 256, 256, 0, stream>>>(rowptr, esrc, enorm, hlin,
                                                         dis, b1, h);
    // layer 2 (mu | logvar fused)
    gemm_mfma<128, true><<<(N_NODES + 63) / 64, 256, 0, stream>>>(h, wcatT, g, N_NODES);
    gather_conv2<<<N_NODES * 32 / 256, 256, 0, stream>>>(rowptr, esrc, enorm, g, dis,
                                                         bmu, blv, outmu, outlv);
}

// Round 7
// 490.599 us; speedup vs baseline: 11.7666x; 1.2907x over previous
//
#include <hip/hip_runtime.h>
#include <hip/hip_bf16.h>

#define N_NODES 100000
#define N_EDGES 1600000
// IN_CH=256, HID_CH=128, OUT_CH=64

typedef __attribute__((ext_vector_type(8))) short short8;
typedef __attribute__((ext_vector_type(8))) unsigned short u16x8;
typedef __attribute__((ext_vector_type(4))) unsigned short u16x4;
typedef __attribute__((ext_vector_type(4))) float f32x4;

__device__ __forceinline__ unsigned short f2bf(float f) {
    union { float f; unsigned u; } v;
    v.f = f;
    unsigned r = v.u + 0x7FFFu + ((v.u >> 16) & 1u);  // RNE
    return (unsigned short)(r >> 16);
}
__device__ __forceinline__ float bf2f(unsigned short u) {
    union { unsigned u; float f; } v;
    v.u = (unsigned)u << 16;
    return v.f;
}

// ---------------- CSR build (1 atomic/edge, 1 random 8B write/edge) ----------------

// rank within destination bucket; counts accumulate in cnt
__global__ void count_rank(const int* __restrict__ dst, int* __restrict__ cnt,
                           int* __restrict__ erank) {
    int e = blockIdx.x * 256 + threadIdx.x;
    if (e < N_EDGES) erank[e] = atomicAdd(&cnt[dst[e]], 1);
}

__global__ __launch_bounds__(256) void scan1(const int* __restrict__ cnt,
                                             int* __restrict__ rowptr,
                                             int* __restrict__ bsum) {
    __shared__ int s[256];
    int tid = threadIdx.x;
    int i = blockIdx.x * 256 + tid;
    int v = (i < N_NODES) ? cnt[i] : 0;
    s[tid] = v;
    __syncthreads();
#pragma unroll
    for (int off = 1; off < 256; off <<= 1) {
        int t = (tid >= off) ? s[tid - off] : 0;
        __syncthreads();
        s[tid] += t;
        __syncthreads();
    }
    if (i < N_NODES) rowptr[i] = s[tid] - v;  // exclusive
    if (tid == 255) bsum[blockIdx.x] = s[255];
}

__global__ __launch_bounds__(512) void scan2(int* __restrict__ bsum, int nb) {
    __shared__ int s[512];
    int tid = threadIdx.x;
    int v = (tid < nb) ? bsum[tid] : 0;
    s[tid] = v;
    __syncthreads();
#pragma unroll
    for (int off = 1; off < 512; off <<= 1) {
        int t = (tid >= off) ? s[tid - off] : 0;
        __syncthreads();
        s[tid] += t;
        __syncthreads();
    }
    if (tid < nb) bsum[tid] = s[tid] - v;  // exclusive
}

__global__ void scan3(int* __restrict__ rowptr, const int* __restrict__ bsum) {
    int i = blockIdx.x * 256 + threadIdx.x;
    if (i < N_NODES) rowptr[i] += bsum[blockIdx.x];
    if (i == 0) rowptr[N_NODES] = N_EDGES;
}

// place packed {src, raw edge weight} at rowptr[dst]+rank — no atomics
__global__ void place(const int* __restrict__ src, const int* __restrict__ dst,
                      const float* __restrict__ ew, const int* __restrict__ rowptr,
                      const int* __restrict__ erank, int2* __restrict__ epack) {
    int e = blockIdx.x * 256 + threadIdx.x;
    if (e >= N_EDGES) return;
    int idx = rowptr[dst[e]] + erank[e];
    epack[idx] = make_int2(src[e], __float_as_int(ew[e]));
}

// per-node row-sum of raw weights -> dis = rsqrt(deg+1)  (self-loop adds 1)
__global__ void deg_dis(const int* __restrict__ rowptr, const int2* __restrict__ epack,
                        float* __restrict__ dis) {
    int n = blockIdx.x * 256 + threadIdx.x;
    if (n >= N_NODES) return;
    float sum = 1.0f;
    int end = rowptr[n + 1];
    for (int j = rowptr[n]; j < end; ++j) sum += __int_as_float(epack[j].y);
    dis[n] = rsqrtf(sum);
}

// ---------------- weight prep: transpose + bf16 ----------------

// W1T[n][k] = bf16(W1[k][n]); W1: 256x128
__global__ void w1_trans(const float* __restrict__ W, unsigned short* __restrict__ WT) {
    int i = blockIdx.x * 256 + threadIdx.x;  // 32768
    int k = i >> 7, n = i & 127;
    WT[n * 256 + k] = f2bf(W[i]);
}

// WcatT[n][k] (128x128): n<64 -> Wmu[k][n], else Wlv[k][n-64]
__global__ void wcat_trans(const float* __restrict__ Wmu, const float* __restrict__ Wlv,
                           unsigned short* __restrict__ WT) {
    int i = blockIdx.x * 256 + threadIdx.x;  // 16384
    int n = i >> 7, k = i & 127;
    float v = (n < 64) ? Wmu[k * 64 + n] : Wlv[k * 64 + (n - 64)];
    WT[n * 128 + k] = f2bf(v);
}

// ---------------- bf16 MFMA GEMM: C[M,128] = A[M,K] @ WT^T ----------------
// WT is [128][K] bf16 (pre-transposed). BM=64 (4 waves x 16 rows), BN=128, BK=32.
// C/D: col = lane&15, row = (lane>>4)*4 + reg  [m89 verified].
template <int K, bool A_BF16>
__global__ __launch_bounds__(256) void gemm_mfma(const void* __restrict__ Aptr,
                                                 const unsigned short* __restrict__ WT,
                                                 unsigned short* __restrict__ C, int M) {
    __shared__ unsigned short As[4 * 64 * 8];   // 4 KB
    __shared__ unsigned short Bs[4 * 128 * 8];  // 8 KB
    const int t = threadIdx.x;
    const int wave = t >> 6, lane = t & 63;
    const int l15 = lane & 15, l4 = lane >> 4;
    const int bm = blockIdx.x * 64;

    f32x4 acc[8] = {};

    const int ar = t >> 2;   // A staging row 0..63
    const int akb = t & 3;   // A staging k-block
    const int bn = t >> 1;   // B staging n 0..127

    for (int k0 = 0; k0 < K; k0 += 32) {
        {
            int row = bm + ar;
            u16x8 av = {};
            if (row < M) {
                if (A_BF16) {
                    av = *reinterpret_cast<const u16x8*>(
                        &((const unsigned short*)Aptr)[(long)row * K + k0 + akb * 8]);
                } else {
                    const float* Af = (const float*)Aptr;
                    float4 v0 = *reinterpret_cast<const float4*>(&Af[(long)row * K + k0 + akb * 8]);
                    float4 v1 = *reinterpret_cast<const float4*>(&Af[(long)row * K + k0 + akb * 8 + 4]);
                    av[0] = f2bf(v0.x); av[1] = f2bf(v0.y); av[2] = f2bf(v0.z); av[3] = f2bf(v0.w);
                    av[4] = f2bf(v1.x); av[5] = f2bf(v1.y); av[6] = f2bf(v1.z); av[7] = f2bf(v1.w);
                }
            }
            *reinterpret_cast<u16x8*>(&As[(akb * 64 + ar) * 8]) = av;
        }
#pragma unroll
        for (int c = 0; c < 2; ++c) {
            int kb = (t & 1) * 2 + c;
            u16x8 bv = *reinterpret_cast<const u16x8*>(&WT[(long)bn * K + k0 + kb * 8]);
            *reinterpret_cast<u16x8*>(&Bs[(kb * 128 + bn) * 8]) = bv;
        }
        __syncthreads();
        short8 a = *reinterpret_cast<const short8*>(&As[(l4 * 64 + wave * 16 + l15) * 8]);
#pragma unroll
        for (int f = 0; f < 8; ++f) {
            short8 b = *reinterpret_cast<const short8*>(&Bs[(l4 * 128 + f * 16 + l15) * 8]);
            acc[f] = __builtin_amdgcn_mfma_f32_16x16x32_bf16(a, b, acc[f], 0, 0, 0);
        }
        __syncthreads();
    }
#pragma unroll
    for (int f = 0; f < 8; ++f) {
#pragma unroll
        for (int r = 0; r < 4; ++r) {
            int row = bm + wave * 16 + l4 * 4 + r;
            if (row < M) C[(long)row * 128 + f * 16 + l15] = f2bf(acc[f][r]);
        }
    }
}

// ---------------- gather-reduce convs (bf16 messages, fused norm) ----------------
// 32 lanes per node, 4 channels (8 B) per lane. norm = dis[src]*ew*dis[dst]
// computed on the fly (dis is a 400 KB L2-resident table).

__global__ __launch_bounds__(256) void gather_conv1(
    const int* __restrict__ rowptr, const int2* __restrict__ epack,
    const unsigned short* __restrict__ hlin, const float* __restrict__ dis,
    const float* __restrict__ bias, unsigned short* __restrict__ hout) {
    int tid = blockIdx.x * 256 + threadIdx.x;  // N_NODES*32
    int n = tid >> 5, q = tid & 31;
    float dv = dis[n], s2 = dv * dv;
    float4 b = *reinterpret_cast<const float4*>(&bias[q * 4]);
    u16x4 sv = *reinterpret_cast<const u16x4*>(&hlin[(long)n * 128 + q * 4]);
    float a0 = bf2f(sv[0]) * s2 + b.x;
    float a1 = bf2f(sv[1]) * s2 + b.y;
    float a2 = bf2f(sv[2]) * s2 + b.z;
    float a3 = bf2f(sv[3]) * s2 + b.w;

    int j = rowptr[n], end = rowptr[n + 1];
    for (; j + 2 <= end; j += 2) {
        int2 p0 = epack[j], p1 = epack[j + 1];
        float w0 = dis[p0.x] * __int_as_float(p0.y) * dv;
        float w1 = dis[p1.x] * __int_as_float(p1.y) * dv;
        u16x4 m0 = *reinterpret_cast<const u16x4*>(&hlin[(long)p0.x * 128 + q * 4]);
        u16x4 m1 = *reinterpret_cast<const u16x4*>(&hlin[(long)p1.x * 128 + q * 4]);
        a0 += bf2f(m0[0]) * w0 + bf2f(m1[0]) * w1;
        a1 += bf2f(m0[1]) * w0 + bf2f(m1[1]) * w1;
        a2 += bf2f(m0[2]) * w0 + bf2f(m1[2]) * w1;
        a3 += bf2f(m0[3]) * w0 + bf2f(m1[3]) * w1;
    }
    if (j < end) {
        int2 p0 = epack[j];
        float w0 = dis[p0.x] * __int_as_float(p0.y) * dv;
        u16x4 m0 = *reinterpret_cast<const u16x4*>(&hlin[(long)p0.x * 128 + q * 4]);
        a0 += bf2f(m0[0]) * w0; a1 += bf2f(m0[1]) * w0;
        a2 += bf2f(m0[2]) * w0; a3 += bf2f(m0[3]) * w0;
    }
    // fused ReLU + bf16 pack (feeds GEMM2 directly)
    u16x4 o;
    o[0] = f2bf(fmaxf(a0, 0.f)); o[1] = f2bf(fmaxf(a1, 0.f));
    o[2] = f2bf(fmaxf(a2, 0.f)); o[3] = f2bf(fmaxf(a3, 0.f));
    *reinterpret_cast<u16x4*>(&hout[(long)n * 128 + q * 4]) = o;
}

// conv2: g[n][0:64] -> mu, g[n][64:128] -> logvar (f32 outputs)
__global__ __launch_bounds__(256) void gather_conv2(
    const int* __restrict__ rowptr, const int2* __restrict__ epack,
    const unsigned short* __restrict__ g, const float* __restrict__ dis,
    const float* __restrict__ bmu, const float* __restrict__ blv,
    float* __restrict__ outmu, float* __restrict__ outlv) {
    int tid = blockIdx.x * 256 + threadIdx.x;  // N_NODES*32
    int n = tid >> 5, q = tid & 31;
    float dv = dis[n], s2 = dv * dv;
    float4 b = (q < 16) ? *reinterpret_cast<const float4*>(&bmu[q * 4])
                        : *reinterpret_cast<const float4*>(&blv[(q - 16) * 4]);
    u16x4 sv = *reinterpret_cast<const u16x4*>(&g[(long)n * 128 + q * 4]);
    float a0 = bf2f(sv[0]) * s2 + b.x;
    float a1 = bf2f(sv[1]) * s2 + b.y;
    float a2 = bf2f(sv[2]) * s2 + b.z;
    float a3 = bf2f(sv[3]) * s2 + b.w;

    int j = rowptr[n], end = rowptr[n + 1];
    for (; j + 2 <= end; j += 2) {
        int2 p0 = epack[j], p1 = epack[j + 1];
        float w0 = dis[p0.x] * __int_as_float(p0.y) * dv;
        float w1 = dis[p1.x] * __int_as_float(p1.y) * dv;
        u16x4 m0 = *reinterpret_cast<const u16x4*>(&g[(long)p0.x * 128 + q * 4]);
        u16x4 m1 = *reinterpret_cast<const u16x4*>(&g[(long)p1.x * 128 + q * 4]);
        a0 += bf2f(m0[0]) * w0 + bf2f(m1[0]) * w1;
        a1 += bf2f(m0[1]) * w0 + bf2f(m1[1]) * w1;
        a2 += bf2f(m0[2]) * w0 + bf2f(m1[2]) * w1;
        a3 += bf2f(m0[3]) * w0 + bf2f(m1[3]) * w1;
    }
    if (j < end) {
        int2 p0 = epack[j];
        float w0 = dis[p0.x] * __int_as_float(p0.y) * dv;
        u16x4 m0 = *reinterpret_cast<const u16x4*>(&g[(long)p0.x * 128 + q * 4]);
        a0 += bf2f(m0[0]) * w0; a1 += bf2f(m0[1]) * w0;
        a2 += bf2f(m0[2]) * w0; a3 += bf2f(m0[3]) * w0;
    }
    float4 o = make_float4(a0, a1, a2, a3);
    if (q < 16)
        *reinterpret_cast<float4*>(&outmu[(long)n * 64 + q * 4]) = o;
    else
        *reinterpret_cast<float4*>(&outlv[(long)n * 64 + (q - 16) * 4]) = o;
}

// ---------------- launch ----------------

extern "C" void kernel_launch(void* const* d_in, const int* in_sizes, int n_in,
                              void* d_out, int out_size, void* d_ws, size_t ws_size,
                              hipStream_t stream) {
    const float* x   = (const float*)d_in[0];
    const int*   ei  = (const int*)d_in[1];
    const float* ew  = (const float*)d_in[2];
    const float* W1  = (const float*)d_in[3];
    const float* b1  = (const float*)d_in[4];
    const float* Wmu = (const float*)d_in[5];
    const float* bmu = (const float*)d_in[6];
    const float* Wlv = (const float*)d_in[7];
    const float* blv = (const float*)d_in[8];

    const int* srcI = ei;            // edge_index[0]
    const int* dstI = ei + N_EDGES;  // edge_index[1]

    float* ws = (float*)d_ws;
    float*          dis    = ws;                               // 100352
    int*            cnt    = (int*)(ws + 100352);              // 100352
    int*            rowptr = (int*)(ws + 200704);              // 100352 (needs 100001)
    int*            bsum   = (int*)(ws + 301056);              // 512
    int*            erank  = (int*)(ws + 301568);              // 1600000
    int2*           epack  = (int2*)(ws + 1901568);            // 1600000 int2 (8B-aligned)
    unsigned short* w1T    = (unsigned short*)(ws + 5101568);  // 32768 ush
    unsigned short* wcatT  = (unsigned short*)(ws + 5117952);  // 16384 ush
    unsigned short* hlin   = (unsigned short*)(ws + 5126144);  // 12.8M ush
    unsigned short* h      = (unsigned short*)(ws + 11526144); // 12.8M ush (ends ~72 MB)
    unsigned short* g      = hlin;  // reuse: hlin dead after gather_conv1
    float* outmu = (float*)d_out;
    float* outlv = outmu + (long)N_NODES * 64;

    const int NB = (N_NODES + 255) / 256;  // 391
    const int EB = N_EDGES / 256;          // 6250

    hipMemsetAsync(cnt, 0, N_NODES * sizeof(int), stream);

    // CSR build: 1 atomic/edge (count_rank), 1 random 8B write/edge (place)
    count_rank<<<EB, 256, 0, stream>>>(dstI, cnt, erank);
    scan1<<<NB, 256, 0, stream>>>(cnt, rowptr, bsum);
    scan2<<<1, 512, 0, stream>>>(bsum, NB);
    scan3<<<NB, 256, 0, stream>>>(rowptr, bsum);
    place<<<EB, 256, 0, stream>>>(srcI, dstI, ew, rowptr, erank, epack);
    deg_dis<<<NB, 256, 0, stream>>>(rowptr, epack, dis);

    w1_trans<<<128, 256, 0, stream>>>(W1, w1T);
    wcat_trans<<<64, 256, 0, stream>>>(Wmu, Wlv, wcatT);

    // layer 1
    gemm_mfma<256, false><<<(N_NODES + 63) / 64, 256, 0, stream>>>(x, w1T, hlin, N_NODES);
    gather_conv1<<<N_NODES * 32 / 256, 256, 0, stream>>>(rowptr, epack, hlin, dis, b1, h);
    // layer 2 (mu | logvar fused)
    gemm_mfma<128, true><<<(N_NODES + 63) / 64, 256, 0, stream>>>(h, wcatT, g, N_NODES);
    gather_conv2<<<N_NODES * 32 / 256, 256, 0, stream>>>(rowptr, epack, g, dis,
                                                         bmu, blv, outmu, outlv);
}